// Round 1
// baseline (1931.110 us; speedup 1.0000x reference)
//
#include <hip/hip_runtime.h>
#include <math.h>

#define VOCAB 50257
#define EMB   1024
#define HID   1024
#define BATCH 64
#define SEQ   512
#define LOGITS_LD 50304   // 786*64, padded

// ---------------------------------------------------------------------------
// Generic tiled fp32 GEMM: C[M=64][N](ldc) = act(A[64][K] @ W[N][K]^T + bias)
// BM=64, BN=64, BK=32; 256 threads; each thread computes a 4x4 micro-tile.
// ---------------------------------------------------------------------------
template <int ACT>  // 0 = none, 1 = tanh
__global__ __launch_bounds__(256) void gemm_atb(
    const float* __restrict__ A, const float* __restrict__ W,
    const float* __restrict__ bias, float* __restrict__ C,
    int N, int K, int ldc)
{
    __shared__ float As[32][65];
    __shared__ float Ws[32][65];
    const int n0  = blockIdx.x * 64;
    const int tid = threadIdx.x;
    const int tm  = tid >> 4;    // 0..15
    const int tn  = tid & 15;    // 0..15

    float acc[4][4] = {};

    for (int k0 = 0; k0 < K; k0 += 32) {
        // Load A tile 64x32 (row-major source, transposed into LDS)
        for (int i = tid; i < 64 * 32; i += 256) {
            int m = i >> 5, kk = i & 31;
            As[kk][m] = A[(size_t)m * K + k0 + kk];
        }
        // Load W tile 64x32
        for (int i = tid; i < 64 * 32; i += 256) {
            int n = i >> 5, kk = i & 31;
            int gn = n0 + n;
            Ws[kk][n] = (gn < N) ? W[(size_t)gn * K + k0 + kk] : 0.0f;
        }
        __syncthreads();
#pragma unroll
        for (int kk = 0; kk < 32; ++kk) {
            float a[4], w[4];
#pragma unroll
            for (int i = 0; i < 4; ++i) a[i] = As[kk][tm * 4 + i];
#pragma unroll
            for (int j = 0; j < 4; ++j) w[j] = Ws[kk][tn * 4 + j];
#pragma unroll
            for (int i = 0; i < 4; ++i)
#pragma unroll
                for (int j = 0; j < 4; ++j)
                    acc[i][j] = fmaf(a[i], w[j], acc[i][j]);
        }
        __syncthreads();
    }

#pragma unroll
    for (int i = 0; i < 4; ++i) {
        int m = tm * 4 + i;
#pragma unroll
        for (int j = 0; j < 4; ++j) {
            int gn = n0 + tn * 4 + j;
            if (gn < N) {
                float v = acc[i][j] + bias[gn];
                if (ACT == 1) v = tanhf(v);
                C[(size_t)m * ldc + gn] = v;
            }
        }
    }
}

// ---------------------------------------------------------------------------
// Embedding gather: x[b][e] = emb[idx[b]][e]
// ---------------------------------------------------------------------------
__global__ __launch_bounds__(256) void embed_k(
    const int* __restrict__ idx, const float* __restrict__ emb,
    float* __restrict__ x)
{
    int b = blockIdx.y;
    int e = blockIdx.x * 256 + threadIdx.x;
    x[(size_t)b * EMB + e] = emb[(size_t)idx[b] * EMB + e];
}

// ---------------------------------------------------------------------------
// GRU gate fusion: given gi[64][3072], gh[64][3072], hprev[64][1024]
// h' = (1-z)*n + z*h ; writes hnew (ws), out_hidden (d_out), optional ci half
// ---------------------------------------------------------------------------
__global__ __launch_bounds__(256) void gru_gate_k(
    const float* __restrict__ gi, const float* __restrict__ gh,
    const float* __restrict__ hprev, float* __restrict__ hnew,
    float* __restrict__ out_hidden, float* __restrict__ ci)
{
    int i = blockIdx.x * 256 + threadIdx.x;   // 0 .. 64*1024
    int b = i >> 10, j = i & 1023;
    size_t base = (size_t)b * 3072 + j;
    float ir = gi[base], iz = gi[base + 1024], in_ = gi[base + 2048];
    float hr = gh[base], hz = gh[base + 1024], hn  = gh[base + 2048];
    float r = 1.0f / (1.0f + expf(-(ir + hr)));
    float z = 1.0f / (1.0f + expf(-(iz + hz)));
    float n = tanhf(in_ + r * hn);
    float h = hprev[i];
    float v = (1.0f - z) * n + z * h;
    hnew[i] = v;
    out_hidden[i] = v;
    if (ci) ci[(size_t)b * 2048 + j] = v;
}

// ---------------------------------------------------------------------------
// Attention scores: scores[b][s] = sum_h h1[b][h] * enc[s][b][h]
// grid (64 b, 8 s-tiles of 64); 4 waves/block, one s per wave step
// ---------------------------------------------------------------------------
__global__ __launch_bounds__(256) void scores_k(
    const float* __restrict__ h1, const float* __restrict__ enc,
    float* __restrict__ scores)
{
    int b = blockIdx.x;
    int stile = blockIdx.y;
    __shared__ float hs[HID];
    for (int i = threadIdx.x; i < HID; i += 256) hs[i] = h1[(size_t)b * HID + i];
    __syncthreads();
    int wave = threadIdx.x >> 6, lane = threadIdx.x & 63;
    for (int si = wave; si < 64; si += 4) {
        int s = stile * 64 + si;
        const float4* e = reinterpret_cast<const float4*>(enc + ((size_t)s * BATCH + b) * HID);
        float acc = 0.0f;
#pragma unroll
        for (int i = 0; i < 4; ++i) {
            int idx4 = lane + i * 64;       // 0..255 float4s
            float4 ev = e[idx4];
            int h = idx4 * 4;
            acc += ev.x * hs[h] + ev.y * hs[h + 1] + ev.z * hs[h + 2] + ev.w * hs[h + 3];
        }
        for (int off = 32; off; off >>= 1) acc += __shfl_down(acc, off);
        if (lane == 0) scores[(size_t)b * SEQ + s] = acc;
    }
}

// ---------------------------------------------------------------------------
// Softmax over S per batch row. 1 block per b; 256 threads, 2 elems each.
// ---------------------------------------------------------------------------
__global__ __launch_bounds__(256) void softmax_s_k(
    const float* __restrict__ scores, float* __restrict__ attn)
{
    int b = blockIdx.x;
    __shared__ float red[8];
    float v0 = scores[(size_t)b * SEQ + threadIdx.x];
    float v1 = scores[(size_t)b * SEQ + 256 + threadIdx.x];
    float m = fmaxf(v0, v1);
    for (int off = 32; off; off >>= 1) m = fmaxf(m, __shfl_xor(m, off));
    int wave = threadIdx.x >> 6, lane = threadIdx.x & 63;
    if (lane == 0) red[wave] = m;
    __syncthreads();
    m = fmaxf(fmaxf(red[0], red[1]), fmaxf(red[2], red[3]));
    float e0 = expf(v0 - m), e1 = expf(v1 - m);
    float ssum = e0 + e1;
    for (int off = 32; off; off >>= 1) ssum += __shfl_xor(ssum, off);
    if (lane == 0) red[4 + wave] = ssum;
    __syncthreads();
    float tot = red[4] + red[5] + red[6] + red[7];
    attn[(size_t)b * SEQ + threadIdx.x] = e0 / tot;
    attn[(size_t)b * SEQ + 256 + threadIdx.x] = e1 / tot;
}

// ---------------------------------------------------------------------------
// Context: ci[b][1024+h] = sum_s attn[b][s] * enc[s][b][h]
// grid (4 h-tiles, 64 b); 256 threads each own one h
// ---------------------------------------------------------------------------
__global__ __launch_bounds__(256) void context_k(
    const float* __restrict__ attn, const float* __restrict__ enc,
    float* __restrict__ ci)
{
    int b = blockIdx.y;
    int h = blockIdx.x * 256 + threadIdx.x;
    __shared__ float a_s[SEQ];
    a_s[threadIdx.x]       = attn[(size_t)b * SEQ + threadIdx.x];
    a_s[256 + threadIdx.x] = attn[(size_t)b * SEQ + 256 + threadIdx.x];
    __syncthreads();
    float acc = 0.0f;
    for (int s = 0; s < SEQ; ++s) {
        acc = fmaf(a_s[s], enc[((size_t)s * BATCH + b) * HID + h], acc);
    }
    ci[(size_t)b * 2048 + 1024 + h] = acc;
}

// ---------------------------------------------------------------------------
// Per-row logit stats: max and sum(exp(x-max)) over VOCAB. 1 block per b.
// ---------------------------------------------------------------------------
__global__ __launch_bounds__(256) void logit_stats_k(
    const float* __restrict__ logits, float* __restrict__ stats, int ldc)
{
    int b = blockIdx.x;
    const float* row = logits + (size_t)b * ldc;
    float m = -INFINITY;
    for (int v = threadIdx.x; v < VOCAB; v += 256) m = fmaxf(m, row[v]);
    __shared__ float red[4];
    for (int off = 32; off; off >>= 1) m = fmaxf(m, __shfl_xor(m, off));
    int wave = threadIdx.x >> 6, lane = threadIdx.x & 63;
    if (lane == 0) red[wave] = m;
    __syncthreads();
    m = fmaxf(fmaxf(red[0], red[1]), fmaxf(red[2], red[3]));
    float ssum = 0.0f;
    for (int v = threadIdx.x; v < VOCAB; v += 256) ssum += expf(row[v] - m);
    for (int off = 32; off; off >>= 1) ssum += __shfl_xor(ssum, off);
    __syncthreads();
    if (lane == 0) red[wave] = ssum;
    __syncthreads();
    float tot = red[0] + red[1] + red[2] + red[3];
    if (threadIdx.x == 0) { stats[b * 2] = m; stats[b * 2 + 1] = tot; }
}

// ---------------------------------------------------------------------------
// Softmax normalize + write output probs
// ---------------------------------------------------------------------------
__global__ __launch_bounds__(256) void softmax_v_k(
    const float* __restrict__ logits, const float* __restrict__ stats,
    float* __restrict__ out, int ldc)
{
    int b = blockIdx.y;
    int v = blockIdx.x * 256 + threadIdx.x;
    if (v < VOCAB) {
        float m = stats[b * 2], tot = stats[b * 2 + 1];
        out[(size_t)b * VOCAB + v] = expf(logits[(size_t)b * ldc + v] - m) / tot;
    }
}

// ---------------------------------------------------------------------------
extern "C" void kernel_launch(void* const* d_in, const int* in_sizes, int n_in,
                              void* d_out, int out_size, void* d_ws, size_t ws_size,
                              hipStream_t stream)
{
    const int*   input_step  = (const int*)  d_in[0];
    const float* last_hidden = (const float*)d_in[1];   // [2][64][1024]
    const float* enc         = (const float*)d_in[2];   // [512][64][1024]
    const float* emb         = (const float*)d_in[3];   // [VOCAB][1024]
    const float* w_ih0       = (const float*)d_in[4];
    const float* w_hh0       = (const float*)d_in[5];
    const float* b_ih0       = (const float*)d_in[6];
    const float* b_hh0       = (const float*)d_in[7];
    const float* w_ih1       = (const float*)d_in[8];
    const float* w_hh1       = (const float*)d_in[9];
    const float* b_ih1       = (const float*)d_in[10];
    const float* b_hh1       = (const float*)d_in[11];
    const float* concat_w    = (const float*)d_in[12];  // [1024][2048]
    const float* concat_b    = (const float*)d_in[13];
    const float* out_w       = (const float*)d_in[14];  // [VOCAB][1024]
    const float* out_b       = (const float*)d_in[15];

    float* out = (float*)d_out;
    float* out_probs  = out;                            // [64][VOCAB]
    float* out_hidden = out + (size_t)BATCH * VOCAB;    // [2][64][1024]

    float* ws = (float*)d_ws;
    float* x      = ws;                         // 64*1024
    float* gi     = x      + 64 * 1024;         // 64*3072
    float* gh     = gi     + 64 * 3072;         // 64*3072
    float* h0     = gh     + 64 * 3072;         // 64*1024
    float* h1     = h0     + 64 * 1024;         // 64*1024
    float* scores = h1     + 64 * 1024;         // 64*512
    float* attn   = scores + 64 * 512;          // 64*512
    float* ci     = attn   + 64 * 512;          // 64*2048
    float* co     = ci     + 64 * 2048;         // 64*1024
    float* logits = co     + 64 * 1024;         // 64*LOGITS_LD
    float* stats  = logits + (size_t)64 * LOGITS_LD;  // 64*2

    // 1. embedding
    embed_k<<<dim3(4, BATCH), 256, 0, stream>>>(input_step, emb, x);

    // 2. GRU layer 0
    gemm_atb<0><<<48, 256, 0, stream>>>(x,           w_ih0, b_ih0, gi, 3 * HID, EMB, 3 * HID);
    gemm_atb<0><<<48, 256, 0, stream>>>(last_hidden, w_hh0, b_hh0, gh, 3 * HID, HID, 3 * HID);
    gru_gate_k<<<256, 256, 0, stream>>>(gi, gh, last_hidden, h0, out_hidden, nullptr);

    // 3. GRU layer 1
    gemm_atb<0><<<48, 256, 0, stream>>>(h0,                     w_ih1, b_ih1, gi, 3 * HID, HID, 3 * HID);
    gemm_atb<0><<<48, 256, 0, stream>>>(last_hidden + 64 * HID, w_hh1, b_hh1, gh, 3 * HID, HID, 3 * HID);
    gru_gate_k<<<256, 256, 0, stream>>>(gi, gh, last_hidden + 64 * HID, h1,
                                        out_hidden + 64 * HID, ci);

    // 4. attention
    scores_k<<<dim3(BATCH, 8), 256, 0, stream>>>(h1, enc, scores);
    softmax_s_k<<<BATCH, 256, 0, stream>>>(scores, attn);
    context_k<<<dim3(4, BATCH), 256, 0, stream>>>(attn, enc, ci);

    // 5. concat projection (tanh)
    gemm_atb<1><<<16, 256, 0, stream>>>(ci, concat_w, concat_b, co, HID, 2 * HID, HID);

    // 6. logits GEMM (dominant: 206 MB of out_w)
    gemm_atb<0><<<786, 256, 0, stream>>>(co, out_w, out_b, logits, VOCAB, HID, LOGITS_LD);

    // 7. softmax over vocab
    logit_stats_k<<<BATCH, 256, 0, stream>>>(logits, stats, LOGITS_LD);
    softmax_v_k<<<dim3((VOCAB + 255) / 256, BATCH), 256, 0, stream>>>(logits, stats, out_probs, LOGITS_LD);
}

// Round 2
// 326.332 us; speedup vs baseline: 5.9176x; 5.9176x over previous
//
#include <hip/hip_runtime.h>
#include <hip/hip_bf16.h>
#include <math.h>

#define VOCAB 50257
#define EMB   1024
#define HID   1024
#define BATCH 64
#define SEQ   512
#define LOGITS_LD 50304   // padded row stride for logits

typedef __attribute__((ext_vector_type(8))) short bf16x8;
typedef __attribute__((ext_vector_type(4))) float f32x4;

__device__ inline short f2bf(float x) {
    __hip_bfloat16 h = __float2bfloat16(x);
    return *reinterpret_cast<short*>(&h);
}

// ---------------------------------------------------------------------------
// MFMA GEMM: C[64][N] = act(A_bf16[64][K] @ W_fp32[N][K]^T + bias)
// Dual problem select via blockIdx.y. 256 thr = 4 waves; tile 64x128;
// each wave: 32 cols (2 colgroups of 16), 4 mtiles of 16 rows.
// A staged in LDS in K-chunks of 512 (64 KB), XOR-swizzled for ds_read_b128.
// ---------------------------------------------------------------------------
#define KC 512

template <int ACT, int OUTBF16>   // ACT: 0 none, 1 tanh
__global__ __launch_bounds__(256) void gemm_mfma(
    const ushort* __restrict__ A0, const float* __restrict__ W0,
    const float* __restrict__ bias0, void* __restrict__ C0, int N0,
    const ushort* __restrict__ A1, const float* __restrict__ W1,
    const float* __restrict__ bias1, void* __restrict__ C1, int N1,
    int K, int ldc)
{
    const ushort* A   = blockIdx.y ? A1 : A0;
    const float*  W   = blockIdx.y ? W1 : W0;
    const float*  bia = blockIdx.y ? bias1 : bias0;
    void*         C   = blockIdx.y ? C1 : C0;
    const int     N   = blockIdx.y ? N1 : N0;

    __shared__ char lds[64 * KC * 2];   // 64 KB

    const int tid  = threadIdx.x;
    const int wv   = tid >> 6;
    const int lane = tid & 63;
    const int rowi = lane & 15;
    const int kgi  = lane >> 4;          // 0..3

    const int col0 = blockIdx.x * 128 + wv * 32;

    f32x4 acc[4][2] = {};

    for (int k0 = 0; k0 < K; k0 += KC) {
        // ---- stage A[64][KC] bf16 into LDS (swizzled) ----
        for (int c = tid; c < 64 * (KC / 8); c += 256) {
            int row = c >> 6;            // KC/8 == 64 chunks per row
            int kc  = c & 63;
            uint4 v = *reinterpret_cast<const uint4*>(A + (size_t)row * K + k0 + kc * 8);
            int off = row * (KC * 2) + kc * 16;
            *reinterpret_cast<uint4*>(lds + (off ^ ((row & 7) << 4))) = v;
        }
        __syncthreads();

        // ---- compute ----
        const int wr0 = min(col0 + rowi, N - 1);
        const int wr1 = min(col0 + 16 + rowi, N - 1);
        for (int ks = 0; ks < KC / 32; ++ks) {
            int kk = ks * 32 + kgi * 8;   // within chunk, multiple of 8
            // W fragments (2 colgroups), fp32 -> bf16
            const float* wp0 = W + (size_t)wr0 * K + k0 + kk;
            const float* wp1 = W + (size_t)wr1 * K + k0 + kk;
            float4 wa0 = *reinterpret_cast<const float4*>(wp0);
            float4 wb0 = *reinterpret_cast<const float4*>(wp0 + 4);
            float4 wa1 = *reinterpret_cast<const float4*>(wp1);
            float4 wb1 = *reinterpret_cast<const float4*>(wp1 + 4);
            bf16x8 b0, b1;
            b0[0]=f2bf(wa0.x); b0[1]=f2bf(wa0.y); b0[2]=f2bf(wa0.z); b0[3]=f2bf(wa0.w);
            b0[4]=f2bf(wb0.x); b0[5]=f2bf(wb0.y); b0[6]=f2bf(wb0.z); b0[7]=f2bf(wb0.w);
            b1[0]=f2bf(wa1.x); b1[1]=f2bf(wa1.y); b1[2]=f2bf(wa1.z); b1[3]=f2bf(wa1.w);
            b1[4]=f2bf(wb1.x); b1[5]=f2bf(wb1.y); b1[6]=f2bf(wb1.z); b1[7]=f2bf(wb1.w);
#pragma unroll
            for (int mt = 0; mt < 4; ++mt) {
                int row = mt * 16 + rowi;
                int off = row * (KC * 2) + kk * 2;
                uint4 av = *reinterpret_cast<const uint4*>(lds + (off ^ ((row & 7) << 4)));
                bf16x8 a = *reinterpret_cast<bf16x8*>(&av);
                acc[mt][0] = __builtin_amdgcn_mfma_f32_16x16x32_bf16(a, b0, acc[mt][0], 0, 0, 0);
                acc[mt][1] = __builtin_amdgcn_mfma_f32_16x16x32_bf16(a, b1, acc[mt][1], 0, 0, 0);
            }
        }
        __syncthreads();
    }

    // ---- epilogue: C/D layout col=lane&15, row=(lane>>4)*4+reg ----
#pragma unroll
    for (int mt = 0; mt < 4; ++mt) {
#pragma unroll
        for (int cg = 0; cg < 2; ++cg) {
            int col = col0 + cg * 16 + rowi;
            if (col < N) {
                float bval = bia[col];
#pragma unroll
                for (int r = 0; r < 4; ++r) {
                    int row = mt * 16 + kgi * 4 + r;
                    float v = acc[mt][cg][r] + bval;
                    if (ACT == 1) v = tanhf(v);
                    if (OUTBF16)
                        ((ushort*)C)[(size_t)row * ldc + col] = (ushort)f2bf(v);
                    else
                        ((float*)C)[(size_t)row * ldc + col] = v;
                }
            }
        }
    }
}

// ---------------------------------------------------------------------------
// Embedding gather -> bf16 A: x_bf[b][e] = bf16(emb[idx[b]][e])
// ---------------------------------------------------------------------------
__global__ __launch_bounds__(256) void embed_k(
    const int* __restrict__ idx, const float* __restrict__ emb,
    ushort* __restrict__ x_bf)
{
    int b = blockIdx.y;
    int e = blockIdx.x * 256 + threadIdx.x;
    x_bf[(size_t)b * EMB + e] = (ushort)f2bf(emb[(size_t)idx[b] * EMB + e]);
}

// ---------------------------------------------------------------------------
// fp32 -> bf16 convert (for last_hidden)
// ---------------------------------------------------------------------------
__global__ __launch_bounds__(256) void cvt_bf_k(
    const float* __restrict__ in, ushort* __restrict__ out, int n)
{
    int i = blockIdx.x * 256 + threadIdx.x;
    if (i < n) out[i] = (ushort)f2bf(in[i]);
}

// ---------------------------------------------------------------------------
// GRU gate fusion. Writes: h fp32 (out_hidden slice), h bf16, optional ci half.
// ---------------------------------------------------------------------------
__global__ __launch_bounds__(256) void gru_gate_k(
    const float* __restrict__ gi, const float* __restrict__ gh,
    const float* __restrict__ hprev, float* __restrict__ out_hidden,
    ushort* __restrict__ h_bf, ushort* __restrict__ ci_bf)
{
    int i = blockIdx.x * 256 + threadIdx.x;   // 0 .. 64*1024
    int b = i >> 10, j = i & 1023;
    size_t base = (size_t)b * 3072 + j;
    float ir = gi[base], iz = gi[base + 1024], in_ = gi[base + 2048];
    float hr = gh[base], hz = gh[base + 1024], hn  = gh[base + 2048];
    float r = 1.0f / (1.0f + expf(-(ir + hr)));
    float z = 1.0f / (1.0f + expf(-(iz + hz)));
    float n = tanhf(in_ + r * hn);
    float h = hprev[i];
    float v = (1.0f - z) * n + z * h;
    out_hidden[i] = v;
    h_bf[i] = (ushort)f2bf(v);
    if (ci_bf) ci_bf[(size_t)b * 2048 + j] = (ushort)f2bf(v);
}

// ---------------------------------------------------------------------------
// Attention scores: scores[b][s] = sum_h h1[b][h] * enc[s][b][h]
// ---------------------------------------------------------------------------
__global__ __launch_bounds__(256) void scores_k(
    const float* __restrict__ h1, const float* __restrict__ enc,
    float* __restrict__ scores)
{
    int b = blockIdx.x;
    int stile = blockIdx.y;
    __shared__ float hs[HID];
    for (int i = threadIdx.x; i < HID; i += 256) hs[i] = h1[(size_t)b * HID + i];
    __syncthreads();
    int wave = threadIdx.x >> 6, lane = threadIdx.x & 63;
    for (int si = wave; si < 64; si += 4) {
        int s = stile * 64 + si;
        const float4* e = reinterpret_cast<const float4*>(enc + ((size_t)s * BATCH + b) * HID);
        float acc = 0.0f;
#pragma unroll
        for (int i = 0; i < 4; ++i) {
            int idx4 = lane + i * 64;
            float4 ev = e[idx4];
            int h = idx4 * 4;
            acc += ev.x * hs[h] + ev.y * hs[h + 1] + ev.z * hs[h + 2] + ev.w * hs[h + 3];
        }
        for (int off = 32; off; off >>= 1) acc += __shfl_down(acc, off);
        if (lane == 0) scores[(size_t)b * SEQ + s] = acc;
    }
}

// ---------------------------------------------------------------------------
// Softmax over S per batch row
// ---------------------------------------------------------------------------
__global__ __launch_bounds__(256) void softmax_s_k(
    const float* __restrict__ scores, float* __restrict__ attn)
{
    int b = blockIdx.x;
    __shared__ float red[8];
    float v0 = scores[(size_t)b * SEQ + threadIdx.x];
    float v1 = scores[(size_t)b * SEQ + 256 + threadIdx.x];
    float m = fmaxf(v0, v1);
    for (int off = 32; off; off >>= 1) m = fmaxf(m, __shfl_xor(m, off));
    int wave = threadIdx.x >> 6, lane = threadIdx.x & 63;
    if (lane == 0) red[wave] = m;
    __syncthreads();
    m = fmaxf(fmaxf(red[0], red[1]), fmaxf(red[2], red[3]));
    float e0 = expf(v0 - m), e1 = expf(v1 - m);
    float ssum = e0 + e1;
    for (int off = 32; off; off >>= 1) ssum += __shfl_xor(ssum, off);
    if (lane == 0) red[4 + wave] = ssum;
    __syncthreads();
    float tot = red[4] + red[5] + red[6] + red[7];
    attn[(size_t)b * SEQ + threadIdx.x] = e0 / tot;
    attn[(size_t)b * SEQ + 256 + threadIdx.x] = e1 / tot;
}

// ---------------------------------------------------------------------------
// Context: ci_bf[b][1024+h] = bf16( sum_s attn[b][s] * enc[s][b][h] )
// ---------------------------------------------------------------------------
__global__ __launch_bounds__(256) void context_k(
    const float* __restrict__ attn, const float* __restrict__ enc,
    ushort* __restrict__ ci_bf)
{
    int b = blockIdx.y;
    int h = blockIdx.x * 256 + threadIdx.x;
    __shared__ float a_s[SEQ];
    a_s[threadIdx.x]       = attn[(size_t)b * SEQ + threadIdx.x];
    a_s[256 + threadIdx.x] = attn[(size_t)b * SEQ + 256 + threadIdx.x];
    __syncthreads();
    float acc0 = 0.0f, acc1 = 0.0f, acc2 = 0.0f, acc3 = 0.0f;
    const float* ep = enc + (size_t)b * HID + h;
    for (int s = 0; s < SEQ; s += 4) {
        acc0 = fmaf(a_s[s],     ep[(size_t)(s)     * BATCH * HID], acc0);
        acc1 = fmaf(a_s[s + 1], ep[(size_t)(s + 1) * BATCH * HID], acc1);
        acc2 = fmaf(a_s[s + 2], ep[(size_t)(s + 2) * BATCH * HID], acc2);
        acc3 = fmaf(a_s[s + 3], ep[(size_t)(s + 3) * BATCH * HID], acc3);
    }
    ci_bf[(size_t)b * 2048 + 1024 + h] = (ushort)f2bf((acc0 + acc1) + (acc2 + acc3));
}

// ---------------------------------------------------------------------------
// Partial logit stats: per (b, chunk of VOCAB/8): max, sum(exp(x-max))
// ---------------------------------------------------------------------------
#define VCHUNK 6283
__global__ __launch_bounds__(256) void stats_part_k(
    const float* __restrict__ logits, float* __restrict__ pmax,
    float* __restrict__ psum, int ldc)
{
    int b = blockIdx.y, ch = blockIdx.x;
    int v0 = ch * VCHUNK;
    int v1 = min(v0 + VCHUNK, VOCAB);
    const float* row = logits + (size_t)b * ldc;
    float m = -INFINITY;
    for (int v = v0 + threadIdx.x; v < v1; v += 256) m = fmaxf(m, row[v]);
    __shared__ float red[4];
    for (int off = 32; off; off >>= 1) m = fmaxf(m, __shfl_xor(m, off));
    int wave = threadIdx.x >> 6, lane = threadIdx.x & 63;
    if (lane == 0) red[wave] = m;
    __syncthreads();
    m = fmaxf(fmaxf(red[0], red[1]), fmaxf(red[2], red[3]));
    float ssum = 0.0f;
    for (int v = v0 + threadIdx.x; v < v1; v += 256) ssum += expf(row[v] - m);
    for (int off = 32; off; off >>= 1) ssum += __shfl_xor(ssum, off);
    __syncthreads();
    if (lane == 0) red[wave] = ssum;
    __syncthreads();
    if (threadIdx.x == 0) {
        pmax[b * 8 + ch] = m;
        psum[b * 8 + ch] = red[0] + red[1] + red[2] + red[3];
    }
}

// ---------------------------------------------------------------------------
// Softmax normalize: combine partials inline, write probs
// ---------------------------------------------------------------------------
__global__ __launch_bounds__(256) void softmax_v_k(
    const float* __restrict__ logits, const float* __restrict__ pmax,
    const float* __restrict__ psum, float* __restrict__ out, int ldc)
{
    int b = blockIdx.y;
    float m = -INFINITY;
#pragma unroll
    for (int i = 0; i < 8; ++i) m = fmaxf(m, pmax[b * 8 + i]);
    float tot = 0.0f;
#pragma unroll
    for (int i = 0; i < 8; ++i) tot += psum[b * 8 + i] * expf(pmax[b * 8 + i] - m);
    float inv = 1.0f / tot;
    int v = blockIdx.x * 1024 + threadIdx.x * 4;
    if (v + 3 < VOCAB) {
        float4 lv = *reinterpret_cast<const float4*>(logits + (size_t)b * ldc + v);
        float4 o;
        o.x = expf(lv.x - m) * inv; o.y = expf(lv.y - m) * inv;
        o.z = expf(lv.z - m) * inv; o.w = expf(lv.w - m) * inv;
        *reinterpret_cast<float4*>(out + (size_t)b * VOCAB + v) = o;
    } else {
        for (int k = 0; k < 4 && v + k < VOCAB; ++k)
            out[(size_t)b * VOCAB + v + k] = expf(logits[(size_t)b * ldc + v + k] - m) * inv;
    }
}

// ---------------------------------------------------------------------------
extern "C" void kernel_launch(void* const* d_in, const int* in_sizes, int n_in,
                              void* d_out, int out_size, void* d_ws, size_t ws_size,
                              hipStream_t stream)
{
    const int*   input_step  = (const int*)  d_in[0];
    const float* last_hidden = (const float*)d_in[1];   // [2][64][1024]
    const float* enc         = (const float*)d_in[2];   // [512][64][1024]
    const float* emb         = (const float*)d_in[3];   // [VOCAB][1024]
    const float* w_ih0       = (const float*)d_in[4];
    const float* w_hh0       = (const float*)d_in[5];
    const float* b_ih0       = (const float*)d_in[6];
    const float* b_hh0       = (const float*)d_in[7];
    const float* w_ih1       = (const float*)d_in[8];
    const float* w_hh1       = (const float*)d_in[9];
    const float* b_ih1       = (const float*)d_in[10];
    const float* b_hh1       = (const float*)d_in[11];
    const float* concat_w    = (const float*)d_in[12];  // [1024][2048]
    const float* concat_b    = (const float*)d_in[13];
    const float* out_w       = (const float*)d_in[14];  // [VOCAB][1024]
    const float* out_b       = (const float*)d_in[15];

    float* out = (float*)d_out;
    float* out_probs  = out;                            // [64][VOCAB]
    float* out_hidden = out + (size_t)BATCH * VOCAB;    // [2][64][1024]

    float* ws = (float*)d_ws;
    float* gi     = ws;                                  // 64*3072
    float* gh     = gi     + 64 * 3072;                  // 64*3072
    float* scores = gh     + 64 * 3072;                  // 64*512
    float* attn   = scores + 64 * 512;                   // 64*512
    float* logits = attn   + 64 * 512;                   // 64*LOGITS_LD
    float* pmax   = logits + (size_t)64 * LOGITS_LD;     // 64*8
    float* psum   = pmax   + 64 * 8;                     // 64*8
    ushort* x_bf  = (ushort*)(psum + 64 * 8);            // 64*1024
    ushort* lh_bf = x_bf  + 64 * 1024;                   // 2*64*1024
    ushort* h0_bf = lh_bf + 2 * 64 * 1024;               // 64*1024
    ushort* ci_bf = h0_bf + 64 * 1024;                   // 64*2048
    ushort* co_bf = ci_bf + 64 * 2048;                   // 64*1024

    // 1. embedding (-> bf16) and last_hidden conversion
    embed_k<<<dim3(4, BATCH), 256, 0, stream>>>(input_step, emb, x_bf);
    cvt_bf_k<<<512, 256, 0, stream>>>(last_hidden, lh_bf, 2 * 64 * 1024);

    // 2. GRU layer 0: dual GEMM (gi and gh in one grid)
    gemm_mfma<0, 0><<<dim3(24, 2), 256, 0, stream>>>(
        x_bf,  w_ih0, b_ih0, gi, 3 * HID,
        lh_bf, w_hh0, b_hh0, gh, 3 * HID, EMB, 3 * HID);
    gru_gate_k<<<256, 256, 0, stream>>>(gi, gh, last_hidden, out_hidden, h0_bf, nullptr);

    // 3. GRU layer 1
    gemm_mfma<0, 0><<<dim3(24, 2), 256, 0, stream>>>(
        h0_bf,               w_ih1, b_ih1, gi, 3 * HID,
        lh_bf + 64 * 1024,   w_hh1, b_hh1, gh, 3 * HID, HID, 3 * HID);
    gru_gate_k<<<256, 256, 0, stream>>>(gi, gh, last_hidden + 64 * HID,
                                        out_hidden + 64 * HID, h0_bf /*unused ok*/, ci_bf);

    // 4. attention (fp32, streaming enc)
    scores_k<<<dim3(BATCH, 8), 256, 0, stream>>>(out_hidden + 64 * HID, enc, scores);
    softmax_s_k<<<BATCH, 256, 0, stream>>>(scores, attn);
    context_k<<<dim3(4, BATCH), 256, 0, stream>>>(attn, enc, ci_bf);

    // 5. concat projection (tanh, bf16 out)
    gemm_mfma<1, 1><<<dim3(8, 1), 256, 0, stream>>>(
        ci_bf, concat_w, concat_b, co_bf, HID,
        ci_bf, concat_w, concat_b, co_bf, HID, 2 * HID, HID);

    // 6. logits GEMM
    gemm_mfma<0, 0><<<dim3(393, 1), 256, 0, stream>>>(
        co_bf, out_w, out_b, logits, VOCAB,
        co_bf, out_w, out_b, logits, VOCAB, HID, LOGITS_LD);

    // 7. softmax over vocab (8-way split stats, then normalize)
    stats_part_k<<<dim3(8, BATCH), 256, 0, stream>>>(logits, pmax, psum, LOGITS_LD);
    softmax_v_k<<<dim3((VOCAB + 1023) / 1024, BATCH), 256, 0, stream>>>(
        logits, pmax, psum, out_probs, LOGITS_LD);
}

// Round 3
// 222.791 us; speedup vs baseline: 8.6678x; 1.4647x over previous
//
#include <hip/hip_runtime.h>
#include <hip/hip_bf16.h>
#include <math.h>

#define VOCAB 50257
#define EMB   1024
#define HID   1024
#define BATCH 64
#define SEQ   512
#define LOGITS_LD 50304

typedef __attribute__((ext_vector_type(8))) short bf16x8;
typedef __attribute__((ext_vector_type(4))) float f32x4;

__device__ inline short f2bf(float x) {
    __hip_bfloat16 h = __float2bfloat16(x);
    return *reinterpret_cast<short*>(&h);
}

// ---------------------------------------------------------------------------
// Direct-stream MFMA GEMM with split-K partials. No LDS, no barriers.
// C_part[kz][64][ldc] = A[64][K-slice] @ W[N][K-slice]^T   (+bias if ADD_BIAS)
// grid: (ntiles64, nproblems, ksplits). 256 thr = 4 waves; wave = 16 cols.
// A is bf16 [64][K] (tiny, L2-broadcast); W fp32 streamed, cvt in-flight.
// ---------------------------------------------------------------------------
template <int ADD_BIAS>
__global__ __launch_bounds__(256) void gemm_sk(
    const ushort* __restrict__ A0, const float* __restrict__ W0,
    const float* __restrict__ bias0, float* __restrict__ C0, int N0,
    const ushort* __restrict__ A1, const float* __restrict__ W1,
    const float* __restrict__ bias1, float* __restrict__ C1, int N1,
    int K, int kslen, int ldc)
{
    const ushort* A   = blockIdx.y ? A1 : A0;
    const float*  W   = blockIdx.y ? W1 : W0;
    const float*  bia = blockIdx.y ? bias1 : bias0;
    const int     N   = blockIdx.y ? N1 : N0;
    float* C = (blockIdx.y ? C1 : C0) + (size_t)blockIdx.z * 64 * ldc;

    const int lane = threadIdx.x & 63;
    const int wv   = threadIdx.x >> 6;
    const int rowi = lane & 15;
    const int kgi  = lane >> 4;
    const int col  = blockIdx.x * 64 + wv * 16 + rowi;
    const int wcol = min(col, N - 1);
    const int kbase = blockIdx.z * kslen;

    f32x4 acc[4] = {};

    const float*  wp = W + (size_t)wcol * K + kbase + kgi * 8;
    const ushort* ap = A + (size_t)rowi * K + kbase + kgi * 8;

    for (int ks = 0; ks < kslen; ks += 32) {
        float4 wa = *reinterpret_cast<const float4*>(wp + ks);
        float4 wb = *reinterpret_cast<const float4*>(wp + ks + 4);
        bf16x8 b;
        b[0] = f2bf(wa.x); b[1] = f2bf(wa.y); b[2] = f2bf(wa.z); b[3] = f2bf(wa.w);
        b[4] = f2bf(wb.x); b[5] = f2bf(wb.y); b[6] = f2bf(wb.z); b[7] = f2bf(wb.w);
#pragma unroll
        for (int mt = 0; mt < 4; ++mt) {
            bf16x8 a = *reinterpret_cast<const bf16x8*>(ap + (size_t)mt * 16 * K + ks);
            acc[mt] = __builtin_amdgcn_mfma_f32_16x16x32_bf16(a, b, acc[mt], 0, 0, 0);
        }
    }

    if (col < N) {
        float bv = ADD_BIAS ? bia[col] : 0.0f;
#pragma unroll
        for (int mt = 0; mt < 4; ++mt)
#pragma unroll
            for (int r = 0; r < 4; ++r) {
                int row = mt * 16 + kgi * 4 + r;
                C[(size_t)row * ldc + col] = acc[mt][r] + bv;
            }
    }
}

// ---------------------------------------------------------------------------
// Prep: embedding gather -> x_bf, last_hidden fp32 -> lh_bf
// ---------------------------------------------------------------------------
__global__ __launch_bounds__(256) void prep_k(
    const int* __restrict__ idx, const float* __restrict__ emb,
    const float* __restrict__ lh, ushort* __restrict__ x_bf,
    ushort* __restrict__ lh_bf)
{
    int i = blockIdx.x * 256 + threadIdx.x;   // 0 .. 196608
    if (i < 65536) {
        int b = i >> 10, e = i & 1023;
        x_bf[i] = (ushort)f2bf(emb[(size_t)idx[b] * EMB + e]);
    } else {
        int k = i - 65536;
        lh_bf[k] = (ushort)f2bf(lh[k]);
    }
}

// ---------------------------------------------------------------------------
// GRU gate fusion over 4 split-K partials of gi and gh.
// ---------------------------------------------------------------------------
__global__ __launch_bounds__(256) void gru_gate4_k(
    const float* __restrict__ pgi, const float* __restrict__ pgh,
    const float* __restrict__ b_ih, const float* __restrict__ b_hh,
    const float* __restrict__ hprev, float* __restrict__ out_hidden,
    ushort* __restrict__ h_bf, ushort* __restrict__ ci_bf)
{
    int i = blockIdx.x * 256 + threadIdx.x;   // 0 .. 65536
    int b = i >> 10, j = i & 1023;
    size_t base = (size_t)b * 3072 + j;
    float ir = b_ih[j], iz = b_ih[j + 1024], in_ = b_ih[j + 2048];
    float hr = b_hh[j], hz = b_hh[j + 1024], hn  = b_hh[j + 2048];
#pragma unroll
    for (int z = 0; z < 4; ++z) {
        size_t o = (size_t)z * 64 * 3072 + base;
        ir += pgi[o]; iz += pgi[o + 1024]; in_ += pgi[o + 2048];
        hr += pgh[o]; hz += pgh[o + 1024]; hn  += pgh[o + 2048];
    }
    float r = 1.0f / (1.0f + expf(-(ir + hr)));
    float z = 1.0f / (1.0f + expf(-(iz + hz)));
    float n = tanhf(in_ + r * hn);
    float v = (1.0f - z) * n + z * hprev[i];
    out_hidden[i] = v;
    if (h_bf)  h_bf[i] = (ushort)f2bf(v);
    if (ci_bf) ci_bf[(size_t)b * 2048 + j] = (ushort)f2bf(v);
}

// ---------------------------------------------------------------------------
// Attention partial: per (s-chunk of 64, b): scores, local softmax, partial ctx.
// enc read once from HBM (pass A); pass B re-reads L2-hot lines.
// ---------------------------------------------------------------------------
__global__ __launch_bounds__(256) void attn_part_k(
    const float* __restrict__ h1, const float* __restrict__ enc,
    float* __restrict__ pctx, float* __restrict__ pm, float* __restrict__ ps)
{
    const int b = blockIdx.y, ck = blockIdx.x;
    __shared__ float hs[HID];
    __shared__ float sc[64];
    __shared__ float redm, redsum;
    const int tid = threadIdx.x, wv = tid >> 6, lane = tid & 63;

    ((float4*)hs)[tid] = ((const float4*)(h1 + (size_t)b * HID))[tid];
    __syncthreads();

    for (int si = wv; si < 64; si += 4) {
        int s = ck * 64 + si;
        const float4* e = (const float4*)(enc + ((size_t)s * BATCH + b) * HID);
        float acc = 0.0f;
#pragma unroll
        for (int i = 0; i < 4; ++i) {
            float4 ev = e[lane + i * 64];
            int h = (lane + i * 64) * 4;
            acc += ev.x * hs[h] + ev.y * hs[h + 1] + ev.z * hs[h + 2] + ev.w * hs[h + 3];
        }
        for (int off = 32; off; off >>= 1) acc += __shfl_down(acc, off);
        if (lane == 0) sc[si] = acc;
    }
    __syncthreads();

    if (tid < 64) {
        float v = sc[tid];
        float m = v;
        for (int off = 32; off; off >>= 1) m = fmaxf(m, __shfl_xor(m, off));
        float p = expf(v - m);
        float sum = p;
        for (int off = 32; off; off >>= 1) sum += __shfl_xor(sum, off);
        sc[tid] = p;
        if (tid == 0) { redm = m; redsum = sum; }
    }
    __syncthreads();

    float c0 = 0, c1 = 0, c2 = 0, c3 = 0;
    const float* ebase = enc + ((size_t)(ck * 64) * BATCH + b) * HID + tid;
    for (int s = 0; s < 64; ++s) {
        const float* ep = ebase + (size_t)s * BATCH * HID;
        float p = sc[s];
        c0 = fmaf(p, ep[0],   c0);
        c1 = fmaf(p, ep[256], c1);
        c2 = fmaf(p, ep[512], c2);
        c3 = fmaf(p, ep[768], c3);
    }
    float* pc = pctx + ((size_t)ck * BATCH + b) * HID + tid;
    pc[0] = c0; pc[256] = c1; pc[512] = c2; pc[768] = c3;
    if (tid == 0) { pm[b * 8 + ck] = redm; ps[b * 8 + ck] = redsum; }
}

// ---------------------------------------------------------------------------
// Attention combine: merge 8 chunk partials -> ci_bf context half.
// ---------------------------------------------------------------------------
__global__ __launch_bounds__(256) void attn_comb_k(
    const float* __restrict__ pctx, const float* __restrict__ pm,
    const float* __restrict__ ps, ushort* __restrict__ ci_bf)
{
    const int b = blockIdx.x, tid = threadIdx.x;
    float m = -INFINITY;
#pragma unroll
    for (int c = 0; c < 8; ++c) m = fmaxf(m, pm[b * 8 + c]);
    float w[8]; float tot = 0.0f;
#pragma unroll
    for (int c = 0; c < 8; ++c) { w[c] = expf(pm[b * 8 + c] - m); tot += ps[b * 8 + c] * w[c]; }
    float inv = 1.0f / tot;
#pragma unroll
    for (int i = 0; i < 4; ++i) {
        int h = tid + i * 256;
        float acc = 0.0f;
#pragma unroll
        for (int c = 0; c < 8; ++c)
            acc += pctx[((size_t)c * BATCH + b) * HID + h] * w[c];
        ci_bf[(size_t)b * 2048 + 1024 + h] = (ushort)f2bf(acc * inv);
    }
}

// ---------------------------------------------------------------------------
// Concat combine: co_bf = bf16(tanh(sum of 8 partials + bias))
// ---------------------------------------------------------------------------
__global__ __launch_bounds__(256) void concat_comb_k(
    const float* __restrict__ pco, const float* __restrict__ bias,
    ushort* __restrict__ co_bf)
{
    int i = blockIdx.x * 256 + threadIdx.x;   // 0 .. 65536
    int j = i & 1023;
    float v = bias[j];
#pragma unroll
    for (int z = 0; z < 8; ++z) v += pco[(size_t)z * 65536 + i];
    co_bf[i] = (ushort)f2bf(tanhf(v));
}

// ---------------------------------------------------------------------------
// Partial logit stats per (b, 1/8 of VOCAB)
// ---------------------------------------------------------------------------
#define VCHUNK 6284
__global__ __launch_bounds__(256) void stats_part_k(
    const float* __restrict__ logits, float* __restrict__ vmax,
    float* __restrict__ vsum, int ldc)
{
    int b = blockIdx.y, ch = blockIdx.x;
    int v0 = ch * VCHUNK;
    int v1 = min(v0 + VCHUNK, VOCAB);
    const float* row = logits + (size_t)b * ldc;
    float m = -INFINITY;
    for (int v = v0 + threadIdx.x; v < v1; v += 256) m = fmaxf(m, row[v]);
    __shared__ float red[4];
    for (int off = 32; off; off >>= 1) m = fmaxf(m, __shfl_xor(m, off));
    int wave = threadIdx.x >> 6, lane = threadIdx.x & 63;
    if (lane == 0) red[wave] = m;
    __syncthreads();
    m = fmaxf(fmaxf(red[0], red[1]), fmaxf(red[2], red[3]));
    float ssum = 0.0f;
    for (int v = v0 + threadIdx.x; v < v1; v += 256) ssum += expf(row[v] - m);
    for (int off = 32; off; off >>= 1) ssum += __shfl_xor(ssum, off);
    __syncthreads();
    if (lane == 0) red[wave] = ssum;
    __syncthreads();
    if (threadIdx.x == 0) {
        vmax[b * 8 + ch] = m;
        vsum[b * 8 + ch] = red[0] + red[1] + red[2] + red[3];
    }
}

// ---------------------------------------------------------------------------
// Softmax normalize over VOCAB
// ---------------------------------------------------------------------------
__global__ __launch_bounds__(256) void softmax_v_k(
    const float* __restrict__ logits, const float* __restrict__ vmax,
    const float* __restrict__ vsum, float* __restrict__ out, int ldc)
{
    int b = blockIdx.y;
    float m = -INFINITY;
#pragma unroll
    for (int i = 0; i < 8; ++i) m = fmaxf(m, vmax[b * 8 + i]);
    float tot = 0.0f;
#pragma unroll
    for (int i = 0; i < 8; ++i) tot += vsum[b * 8 + i] * expf(vmax[b * 8 + i] - m);
    float inv = 1.0f / tot;
    int v = blockIdx.x * 1024 + threadIdx.x * 4;
    if (v + 3 < VOCAB) {
        float4 lv = *reinterpret_cast<const float4*>(logits + (size_t)b * ldc + v);
        float4 o;
        o.x = expf(lv.x - m) * inv; o.y = expf(lv.y - m) * inv;
        o.z = expf(lv.z - m) * inv; o.w = expf(lv.w - m) * inv;
        *reinterpret_cast<float4*>(out + (size_t)b * VOCAB + v) = o;
    } else {
        for (int k = 0; k < 4 && v + k < VOCAB; ++k)
            out[(size_t)b * VOCAB + v + k] = expf(logits[(size_t)b * ldc + v + k] - m) * inv;
    }
}

// ---------------------------------------------------------------------------
extern "C" void kernel_launch(void* const* d_in, const int* in_sizes, int n_in,
                              void* d_out, int out_size, void* d_ws, size_t ws_size,
                              hipStream_t stream)
{
    const int*   input_step  = (const int*)  d_in[0];
    const float* last_hidden = (const float*)d_in[1];
    const float* enc         = (const float*)d_in[2];
    const float* emb         = (const float*)d_in[3];
    const float* w_ih0       = (const float*)d_in[4];
    const float* w_hh0       = (const float*)d_in[5];
    const float* b_ih0       = (const float*)d_in[6];
    const float* b_hh0       = (const float*)d_in[7];
    const float* w_ih1       = (const float*)d_in[8];
    const float* w_hh1       = (const float*)d_in[9];
    const float* b_ih1       = (const float*)d_in[10];
    const float* b_hh1       = (const float*)d_in[11];
    const float* concat_w    = (const float*)d_in[12];
    const float* concat_b    = (const float*)d_in[13];
    const float* out_w       = (const float*)d_in[14];
    const float* out_b       = (const float*)d_in[15];

    float* out = (float*)d_out;
    float* out_probs  = out;
    float* out_hidden = out + (size_t)BATCH * VOCAB;

    float* ws = (float*)d_ws;
    float* pgi    = ws;                                   // 4*64*3072
    float* pgh    = pgi    + 4 * 64 * 3072;               // 4*64*3072
    float* pctx   = pgh    + 4 * 64 * 3072;               // 8*64*1024
    float* pco    = pctx   + 8 * 64 * 1024;               // 8*64*1024
    float* pm     = pco    + 8 * 64 * 1024;               // 64*8
    float* ps     = pm     + 64 * 8;                      // 64*8
    float* vmax   = ps     + 64 * 8;                      // 64*8
    float* vsum   = vmax   + 64 * 8;                      // 64*8
    float* logits = vsum   + 64 * 8;                      // 64*LOGITS_LD
    ushort* x_bf  = (ushort*)(logits + (size_t)64 * LOGITS_LD);
    ushort* lh_bf = x_bf  + 64 * 1024;                    // 2*64*1024
    ushort* h0_bf = lh_bf + 2 * 64 * 1024;                // 64*1024
    ushort* ci_bf = h0_bf + 64 * 1024;                    // 64*2048
    ushort* co_bf = ci_bf + 64 * 2048;                    // 64*1024

    // 1. prep: embed gather + lh conversion
    prep_k<<<768, 256, 0, stream>>>(input_step, emb, last_hidden, x_bf, lh_bf);

    // 2. GRU layer 0: dual GEMM, split-K 4
    gemm_sk<0><<<dim3(48, 2, 4), 256, 0, stream>>>(
        x_bf,  w_ih0, nullptr, pgi, 3 * HID,
        lh_bf, w_hh0, nullptr, pgh, 3 * HID, EMB, 256, 3 * HID);
    gru_gate4_k<<<256, 256, 0, stream>>>(pgi, pgh, b_ih0, b_hh0, last_hidden,
                                         out_hidden, h0_bf, nullptr);

    // 3. GRU layer 1
    gemm_sk<0><<<dim3(48, 2, 4), 256, 0, stream>>>(
        h0_bf,             w_ih1, nullptr, pgi, 3 * HID,
        lh_bf + 64 * 1024, w_hh1, nullptr, pgh, 3 * HID, HID, 256, 3 * HID);
    gru_gate4_k<<<256, 256, 0, stream>>>(pgi, pgh, b_ih1, b_hh1, last_hidden + 64 * HID,
                                         out_hidden + 64 * HID, nullptr, ci_bf);

    // 4. attention: partial-flash over 8 s-chunks, then combine
    attn_part_k<<<dim3(8, BATCH), 256, 0, stream>>>(out_hidden + 64 * HID, enc, pctx, pm, ps);
    attn_comb_k<<<BATCH, 256, 0, stream>>>(pctx, pm, ps, ci_bf);

    // 5. concat projection: split-K 8 + combine (tanh)
    gemm_sk<0><<<dim3(16, 1, 8), 256, 0, stream>>>(
        ci_bf, concat_w, nullptr, pco, HID,
        ci_bf, concat_w, nullptr, pco, HID, 2 * HID, 256, HID);
    concat_comb_k<<<256, 256, 0, stream>>>(pco, concat_b, co_bf);

    // 6. logits GEMM: 786 blocks, full K, bias fused
    gemm_sk<1><<<dim3(786, 1, 1), 256, 0, stream>>>(
        co_bf, out_w, out_b, logits, VOCAB,
        co_bf, out_w, out_b, logits, VOCAB, HID, HID, LOGITS_LD);

    // 7. vocab softmax
    stats_part_k<<<dim3(8, BATCH), 256, 0, stream>>>(logits, vmax, vsum, LOGITS_LD);
    softmax_v_k<<<dim3((VOCAB + 1023) / 1024, BATCH), 256, 0, stream>>>(
        logits, vmax, vsum, out_probs, LOGITS_LD);
}

// Round 4
// 211.605 us; speedup vs baseline: 9.1260x; 1.0529x over previous
//
#include <hip/hip_runtime.h>
#include <hip/hip_bf16.h>
#include <math.h>

#define VOCAB 50257
#define EMB   1024
#define HID   1024
#define BATCH 64
#define SEQ   512
#define LOGITS_LD 50304
#define SCH   16      // s-rows per attention chunk
#define NCHUNK (SEQ / SCH)   // 32

typedef __attribute__((ext_vector_type(8))) short bf16x8;
typedef __attribute__((ext_vector_type(4))) float f32x4;

__device__ inline short f2bf(float x) {
    __hip_bfloat16 h = __float2bfloat16(x);
    return *reinterpret_cast<short*>(&h);
}

// ---------------------------------------------------------------------------
// Direct-stream MFMA GEMM, split-K partials, depth-1 register prefetch.
// C_part[kz][64][ldc] = A[64][Kslice] @ W[N][Kslice]^T (+bias if ADD_BIAS)
// grid (ntiles64, nproblems, ksplits); 256 thr = 4 waves; wave = 16 cols.
// ---------------------------------------------------------------------------
template <int ADD_BIAS, int KSLEN>
__global__ __launch_bounds__(256) void gemm_sk(
    const ushort* __restrict__ A0, const float* __restrict__ W0,
    const float* __restrict__ bias0, float* __restrict__ C0, int N0,
    const ushort* __restrict__ A1, const float* __restrict__ W1,
    const float* __restrict__ bias1, float* __restrict__ C1, int N1,
    int K, int ldc)
{
    const ushort* A   = blockIdx.y ? A1 : A0;
    const float*  W   = blockIdx.y ? W1 : W0;
    const float*  bia = blockIdx.y ? bias1 : bias0;
    const int     N   = blockIdx.y ? N1 : N0;
    float* C = (blockIdx.y ? C1 : C0) + (size_t)blockIdx.z * 64 * ldc;

    const int lane = threadIdx.x & 63;
    const int wv   = threadIdx.x >> 6;
    const int rowi = lane & 15;
    const int kgi  = lane >> 4;
    const int col  = blockIdx.x * 64 + wv * 16 + rowi;
    const int wcol = min(col, N - 1);

    const float*  wp = W + (size_t)wcol * K + (size_t)blockIdx.z * KSLEN + kgi * 8;
    const ushort* ap = A + (size_t)rowi * K + (size_t)blockIdx.z * KSLEN + kgi * 8;

    f32x4 acc[4] = {};

    float4 wa = *reinterpret_cast<const float4*>(wp);
    float4 wb = *reinterpret_cast<const float4*>(wp + 4);
    bf16x8 a0 = *reinterpret_cast<const bf16x8*>(ap);
    bf16x8 a1 = *reinterpret_cast<const bf16x8*>(ap + 16 * K);
    bf16x8 a2 = *reinterpret_cast<const bf16x8*>(ap + 32 * K);
    bf16x8 a3 = *reinterpret_cast<const bf16x8*>(ap + 48 * K);

#pragma unroll 4
    for (int ks = 32; ks <= KSLEN; ks += 32) {
        float4 nwa = {}, nwb = {};
        bf16x8 n0 = {}, n1 = {}, n2 = {}, n3 = {};
        if (ks < KSLEN) {
            nwa = *reinterpret_cast<const float4*>(wp + ks);
            nwb = *reinterpret_cast<const float4*>(wp + ks + 4);
            n0 = *reinterpret_cast<const bf16x8*>(ap + ks);
            n1 = *reinterpret_cast<const bf16x8*>(ap + 16 * K + ks);
            n2 = *reinterpret_cast<const bf16x8*>(ap + 32 * K + ks);
            n3 = *reinterpret_cast<const bf16x8*>(ap + 48 * K + ks);
        }
        bf16x8 b;
        b[0] = f2bf(wa.x); b[1] = f2bf(wa.y); b[2] = f2bf(wa.z); b[3] = f2bf(wa.w);
        b[4] = f2bf(wb.x); b[5] = f2bf(wb.y); b[6] = f2bf(wb.z); b[7] = f2bf(wb.w);
        acc[0] = __builtin_amdgcn_mfma_f32_16x16x32_bf16(a0, b, acc[0], 0, 0, 0);
        acc[1] = __builtin_amdgcn_mfma_f32_16x16x32_bf16(a1, b, acc[1], 0, 0, 0);
        acc[2] = __builtin_amdgcn_mfma_f32_16x16x32_bf16(a2, b, acc[2], 0, 0, 0);
        acc[3] = __builtin_amdgcn_mfma_f32_16x16x32_bf16(a3, b, acc[3], 0, 0, 0);
        wa = nwa; wb = nwb; a0 = n0; a1 = n1; a2 = n2; a3 = n3;
    }

    if (col < N) {
        float bv = ADD_BIAS ? bia[col] : 0.0f;
#pragma unroll
        for (int mt = 0; mt < 4; ++mt)
#pragma unroll
            for (int r = 0; r < 4; ++r) {
                int row = mt * 16 + kgi * 4 + r;
                C[(size_t)row * ldc + col] = acc[mt][r] + bv;
            }
    }
}

// ---------------------------------------------------------------------------
// Prep: embedding gather -> x_bf, last_hidden fp32 -> lh_bf
// ---------------------------------------------------------------------------
__global__ __launch_bounds__(256) void prep_k(
    const int* __restrict__ idx, const float* __restrict__ emb,
    const float* __restrict__ lh, ushort* __restrict__ x_bf,
    ushort* __restrict__ lh_bf)
{
    int i = blockIdx.x * 256 + threadIdx.x;
    if (i < 65536) {
        int b = i >> 10, e = i & 1023;
        x_bf[i] = (ushort)f2bf(emb[(size_t)idx[b] * EMB + e]);
    } else {
        int k = i - 65536;
        lh_bf[k] = (ushort)f2bf(lh[k]);
    }
}

// ---------------------------------------------------------------------------
// GRU gate fusion over 4 split-K partials.
// ---------------------------------------------------------------------------
__global__ __launch_bounds__(256) void gru_gate4_k(
    const float* __restrict__ pgi, const float* __restrict__ pgh,
    const float* __restrict__ b_ih, const float* __restrict__ b_hh,
    const float* __restrict__ hprev, float* __restrict__ out_hidden,
    ushort* __restrict__ h_bf, ushort* __restrict__ ci_bf)
{
    int i = blockIdx.x * 256 + threadIdx.x;
    int b = i >> 10, j = i & 1023;
    size_t base = (size_t)b * 3072 + j;
    float ir = b_ih[j], iz = b_ih[j + 1024], in_ = b_ih[j + 2048];
    float hr = b_hh[j], hz = b_hh[j + 1024], hn  = b_hh[j + 2048];
#pragma unroll
    for (int z = 0; z < 4; ++z) {
        size_t o = (size_t)z * 64 * 3072 + base;
        ir += pgi[o]; iz += pgi[o + 1024]; in_ += pgi[o + 2048];
        hr += pgh[o]; hz += pgh[o + 1024]; hn  += pgh[o + 2048];
    }
    float r = 1.0f / (1.0f + expf(-(ir + hr)));
    float z = 1.0f / (1.0f + expf(-(iz + hz)));
    float n = tanhf(in_ + r * hn);
    float v = (1.0f - z) * n + z * hprev[i];
    out_hidden[i] = v;
    if (h_bf)  h_bf[i] = (ushort)f2bf(v);
    if (ci_bf) ci_bf[(size_t)b * 2048 + j] = (ushort)f2bf(v);
}

// ---------------------------------------------------------------------------
// Single-pass flash attention chunk: per (chunk of 16 s, b):
// stage enc rows in LDS once, scores from LDS, local softmax, context from LDS.
// ---------------------------------------------------------------------------
__global__ __launch_bounds__(256) void attn_fused_k(
    const float* __restrict__ h1, const float* __restrict__ enc,
    float* __restrict__ pctx, float* __restrict__ pm, float* __restrict__ ps)
{
    const int b = blockIdx.y, ck = blockIdx.x;
    __shared__ float hs[HID];
    __shared__ float es[SCH][HID];
    __shared__ float sc[SCH];
    const int tid = threadIdx.x, wv = tid >> 6, lane = tid & 63;

    ((float4*)hs)[tid] = ((const float4*)(h1 + (size_t)b * HID))[tid];
    const float* ebase = enc + ((size_t)(ck * SCH) * BATCH + b) * HID;
#pragma unroll
    for (int i = 0; i < SCH; ++i) {
        int idx = tid + i * 256;
        int r = idx >> 8, c = idx & 255;
        ((float4*)es[r])[c] = ((const float4*)(ebase + (size_t)r * BATCH * HID))[c];
    }
    __syncthreads();

    // scores: wave wv computes rows wv*4 .. wv*4+3
#pragma unroll
    for (int i = 0; i < 4; ++i) {
        int r = wv * 4 + i;
        float acc = 0.0f;
#pragma unroll
        for (int seg = 0; seg < 4; ++seg) {
            float4 ev = ((const float4*)es[r])[lane + seg * 64];
            float4 hv = ((const float4*)hs)[lane + seg * 64];
            acc += ev.x * hv.x + ev.y * hv.y + ev.z * hv.z + ev.w * hv.w;
        }
        for (int off = 32; off; off >>= 1) acc += __shfl_down(acc, off);
        if (lane == 0) sc[r] = acc;
    }
    __syncthreads();

    // local softmax over 16 scores (redundant per-thread, cheap)
    float m = sc[0];
#pragma unroll
    for (int s = 1; s < SCH; ++s) m = fmaxf(m, sc[s]);
    float p[SCH];
    float sum = 0.0f;
#pragma unroll
    for (int s = 0; s < SCH; ++s) { p[s] = expf(sc[s] - m); sum += p[s]; }

    // context: each thread owns float4 at h-index tid
    float4 cacc = {0.0f, 0.0f, 0.0f, 0.0f};
#pragma unroll
    for (int s = 0; s < SCH; ++s) {
        float4 ev = ((const float4*)es[s])[tid];
        cacc.x += p[s] * ev.x; cacc.y += p[s] * ev.y;
        cacc.z += p[s] * ev.z; cacc.w += p[s] * ev.w;
    }
    ((float4*)(pctx + ((size_t)ck * BATCH + b) * HID))[tid] = cacc;
    if (tid == 0) { pm[b * NCHUNK + ck] = m; ps[b * NCHUNK + ck] = sum; }
}

// ---------------------------------------------------------------------------
// Attention combine: merge 32 chunk partials -> ci_bf context half.
// ---------------------------------------------------------------------------
__global__ __launch_bounds__(256) void attn_comb_k(
    const float* __restrict__ pctx, const float* __restrict__ pm,
    const float* __restrict__ ps, ushort* __restrict__ ci_bf)
{
    const int b = blockIdx.x, tid = threadIdx.x;
    float m = -INFINITY;
#pragma unroll
    for (int c = 0; c < NCHUNK; ++c) m = fmaxf(m, pm[b * NCHUNK + c]);
    float w[NCHUNK]; float tot = 0.0f;
#pragma unroll
    for (int c = 0; c < NCHUNK; ++c) {
        w[c] = expf(pm[b * NCHUNK + c] - m);
        tot += ps[b * NCHUNK + c] * w[c];
    }
    float inv = 1.0f / tot;
    float4 acc = {0.0f, 0.0f, 0.0f, 0.0f};
#pragma unroll
    for (int c = 0; c < NCHUNK; ++c) {
        float4 v = ((const float4*)(pctx + ((size_t)c * BATCH + b) * HID))[tid];
        acc.x += w[c] * v.x; acc.y += w[c] * v.y;
        acc.z += w[c] * v.z; acc.w += w[c] * v.w;
    }
    ushort* o = ci_bf + (size_t)b * 2048 + 1024 + tid * 4;
    o[0] = (ushort)f2bf(acc.x * inv); o[1] = (ushort)f2bf(acc.y * inv);
    o[2] = (ushort)f2bf(acc.z * inv); o[3] = (ushort)f2bf(acc.w * inv);
}

// ---------------------------------------------------------------------------
// Concat combine: co_bf = bf16(tanh(sum of 8 partials + bias))
// ---------------------------------------------------------------------------
__global__ __launch_bounds__(256) void concat_comb_k(
    const float* __restrict__ pco, const float* __restrict__ bias,
    ushort* __restrict__ co_bf)
{
    int i = blockIdx.x * 256 + threadIdx.x;
    int j = i & 1023;
    float v = bias[j];
#pragma unroll
    for (int z = 0; z < 8; ++z) v += pco[(size_t)z * 65536 + i];
    co_bf[i] = (ushort)f2bf(tanhf(v));
}

// ---------------------------------------------------------------------------
// Partial logit stats per (b, 1/8 of VOCAB)
// ---------------------------------------------------------------------------
#define VCHUNK 6284
__global__ __launch_bounds__(256) void stats_part_k(
    const float* __restrict__ logits, float* __restrict__ vmax,
    float* __restrict__ vsum, int ldc)
{
    int b = blockIdx.y, ch = blockIdx.x;
    int v0 = ch * VCHUNK;
    int v1 = min(v0 + VCHUNK, VOCAB);
    const float* row = logits + (size_t)b * ldc;
    float m = -INFINITY;
    for (int v = v0 + threadIdx.x; v < v1; v += 256) m = fmaxf(m, row[v]);
    __shared__ float red[4];
    for (int off = 32; off; off >>= 1) m = fmaxf(m, __shfl_xor(m, off));
    int wave = threadIdx.x >> 6, lane = threadIdx.x & 63;
    if (lane == 0) red[wave] = m;
    __syncthreads();
    m = fmaxf(fmaxf(red[0], red[1]), fmaxf(red[2], red[3]));
    float ssum = 0.0f;
    for (int v = v0 + threadIdx.x; v < v1; v += 256) ssum += expf(row[v] - m);
    for (int off = 32; off; off >>= 1) ssum += __shfl_xor(ssum, off);
    __syncthreads();
    if (lane == 0) red[wave] = ssum;
    __syncthreads();
    if (threadIdx.x == 0) {
        vmax[b * 8 + ch] = m;
        vsum[b * 8 + ch] = red[0] + red[1] + red[2] + red[3];
    }
}

// ---------------------------------------------------------------------------
// Softmax normalize over VOCAB
// ---------------------------------------------------------------------------
__global__ __launch_bounds__(256) void softmax_v_k(
    const float* __restrict__ logits, const float* __restrict__ vmax,
    const float* __restrict__ vsum, float* __restrict__ out, int ldc)
{
    int b = blockIdx.y;
    float m = -INFINITY;
#pragma unroll
    for (int i = 0; i < 8; ++i) m = fmaxf(m, vmax[b * 8 + i]);
    float tot = 0.0f;
#pragma unroll
    for (int i = 0; i < 8; ++i) tot += vsum[b * 8 + i] * expf(vmax[b * 8 + i] - m);
    float inv = 1.0f / tot;
    int v = blockIdx.x * 1024 + threadIdx.x * 4;
    if (v + 3 < VOCAB) {
        float4 lv = *reinterpret_cast<const float4*>(logits + (size_t)b * ldc + v);
        float4 o;
        o.x = expf(lv.x - m) * inv; o.y = expf(lv.y - m) * inv;
        o.z = expf(lv.z - m) * inv; o.w = expf(lv.w - m) * inv;
        *reinterpret_cast<float4*>(out + (size_t)b * VOCAB + v) = o;
    } else {
        for (int k = 0; k < 4 && v + k < VOCAB; ++k)
            out[(size_t)b * VOCAB + v + k] = expf(logits[(size_t)b * ldc + v + k] - m) * inv;
    }
}

// ---------------------------------------------------------------------------
extern "C" void kernel_launch(void* const* d_in, const int* in_sizes, int n_in,
                              void* d_out, int out_size, void* d_ws, size_t ws_size,
                              hipStream_t stream)
{
    const int*   input_step  = (const int*)  d_in[0];
    const float* last_hidden = (const float*)d_in[1];
    const float* enc         = (const float*)d_in[2];
    const float* emb         = (const float*)d_in[3];
    const float* w_ih0       = (const float*)d_in[4];
    const float* w_hh0       = (const float*)d_in[5];
    const float* b_ih0       = (const float*)d_in[6];
    const float* b_hh0       = (const float*)d_in[7];
    const float* w_ih1       = (const float*)d_in[8];
    const float* w_hh1       = (const float*)d_in[9];
    const float* b_ih1       = (const float*)d_in[10];
    const float* b_hh1       = (const float*)d_in[11];
    const float* concat_w    = (const float*)d_in[12];
    const float* concat_b    = (const float*)d_in[13];
    const float* out_w       = (const float*)d_in[14];
    const float* out_b       = (const float*)d_in[15];

    float* out = (float*)d_out;
    float* out_probs  = out;
    float* out_hidden = out + (size_t)BATCH * VOCAB;

    float* ws = (float*)d_ws;
    float* pgi    = ws;                                   // 4*64*3072
    float* pgh    = pgi    + 4 * 64 * 3072;               // 4*64*3072
    float* pctx   = pgh    + 4 * 64 * 3072;               // 32*64*1024
    float* pco    = pctx   + NCHUNK * 64 * 1024;          // 8*64*1024
    float* pm     = pco    + 8 * 64 * 1024;               // 64*32
    float* ps     = pm     + 64 * NCHUNK;                 // 64*32
    float* vmax   = ps     + 64 * NCHUNK;                 // 64*8
    float* vsum   = vmax   + 64 * 8;                      // 64*8
    float* logits = vsum   + 64 * 8;                      // 64*LOGITS_LD
    ushort* x_bf  = (ushort*)(logits + (size_t)64 * LOGITS_LD);
    ushort* lh_bf = x_bf  + 64 * 1024;
    ushort* h0_bf = lh_bf + 2 * 64 * 1024;
    ushort* ci_bf = h0_bf + 64 * 1024;
    ushort* co_bf = ci_bf + 64 * 2048;

    // 1. prep
    prep_k<<<768, 256, 0, stream>>>(input_step, emb, last_hidden, x_bf, lh_bf);

    // 2. GRU layer 0 (dual GEMM, split-K 4)
    gemm_sk<0, 256><<<dim3(48, 2, 4), 256, 0, stream>>>(
        x_bf,  w_ih0, nullptr, pgi, 3 * HID,
        lh_bf, w_hh0, nullptr, pgh, 3 * HID, EMB, 3 * HID);
    gru_gate4_k<<<256, 256, 0, stream>>>(pgi, pgh, b_ih0, b_hh0, last_hidden,
                                         out_hidden, h0_bf, nullptr);

    // 3. GRU layer 1
    gemm_sk<0, 256><<<dim3(48, 2, 4), 256, 0, stream>>>(
        h0_bf,             w_ih1, nullptr, pgi, 3 * HID,
        lh_bf + 64 * 1024, w_hh1, nullptr, pgh, 3 * HID, HID, 3 * HID);
    gru_gate4_k<<<256, 256, 0, stream>>>(pgi, pgh, b_ih1, b_hh1, last_hidden + 64 * HID,
                                         out_hidden + 64 * HID, nullptr, ci_bf);

    // 4. attention: single-pass flash over 32 chunks of 16, then combine
    attn_fused_k<<<dim3(NCHUNK, BATCH), 256, 0, stream>>>(
        out_hidden + 64 * HID, enc, pctx, pm, ps);
    attn_comb_k<<<BATCH, 256, 0, stream>>>(pctx, pm, ps, ci_bf);

    // 5. concat projection: split-K 8 + combine (tanh)
    gemm_sk<0, 256><<<dim3(16, 1, 8), 256, 0, stream>>>(
        ci_bf, concat_w, nullptr, pco, HID,
        ci_bf, concat_w, nullptr, pco, HID, 2 * HID, HID);
    concat_comb_k<<<256, 256, 0, stream>>>(pco, concat_b, co_bf);

    // 6. logits GEMM (full K, bias fused, prefetch-pipelined)
    gemm_sk<1, 1024><<<dim3(786, 1, 1), 256, 0, stream>>>(
        co_bf, out_w, out_b, logits, VOCAB,
        co_bf, out_w, out_b, logits, VOCAB, HID, LOGITS_LD);

    // 7. vocab softmax
    stats_part_k<<<dim3(8, BATCH), 256, 0, stream>>>(logits, vmax, vsum, LOGITS_LD);
    softmax_v_k<<<dim3((VOCAB + 1023) / 1024, BATCH), 256, 0, stream>>>(
        logits, vmax, vsum, out_probs, LOGITS_LD);
}